// Round 1
// baseline (442.906 us; speedup 1.0000x reference)
//
#include <hip/hip_runtime.h>

// LengthRegulator: B=32, T=1024, D=384, MAXLEN=8192 (fixed by harness).
// v5: 8 frames per 192-thread block. A block's 8 frames own CONSECUTIVE
// output rows [cum[f0-1], cum[f0+7]) -> one contiguous ~90 KB store stream
// per block (fill-kernel-like). All 8 source rows prefetched up-front
// (independent loads, latency overlapped); 9 wave-uniform scalar boundary
// loads. Grid shrinks 33792 -> 5120 blocks to kill per-block startup
// latency, which held v4 at ~2.6 TB/s vs the 6.3 TB/s the harness fill
// proves on this same buffer. Nontemporal stores keep x L3-resident.

#define B_    32
#define T_    1024
#define D_    384
#define ML_   8192
#define D4_   (D_ / 4)     // 96 float4 per row
#define NTHR  192          // 2 rows per store window, exactly 3 waves
#define NFILL 32           // fill-role blocks per batch
#define G_    8            // frames per expand block
#define NEXP  (T_ / G_)    // 128 expand blocks per batch

typedef float f32x4 __attribute__((ext_vector_type(4)));

// --- Kernel 1: per-batch inclusive scan of clamped durations -------------
__global__ __launch_bounds__(T_) void lr_scan(const int* __restrict__ dur,
                                              int* __restrict__ cum,
                                              float* __restrict__ total_out) {
    const int b = blockIdx.x;
    const int t = threadIdx.x;
    const int lane = t & 63;
    const int wave = t >> 6;

    int v = dur[b * T_ + t];
    v = v > 0 ? v : 0;

    for (int off = 1; off < 64; off <<= 1) {
        int n = __shfl_up(v, off, 64);
        if (lane >= off) v += n;
    }

    __shared__ int wsum[16];
    if (lane == 63) wsum[wave] = v;
    __syncthreads();

    if (wave == 0 && lane < 16) {
        int w = wsum[lane];
        for (int off = 1; off < 16; off <<= 1) {
            int n = __shfl_up(w, off, 64);
            if (lane >= off) w += n;
        }
        wsum[lane] = w;
    }
    __syncthreads();

    int c = v + (wave > 0 ? wsum[wave - 1] : 0);
    cum[b * T_ + t] = c;
    if (t == T_ - 1) {
        total_out[b] = (float)c;   // total <= 15360, exact in fp32
    }
}

// --- Kernel 2: expand (8 frames/block) + tail-fill ------------------------
// grid = (NEXP + NFILL, B_), 192 threads. bi < NEXP: expand frames
// [bi*8, bi*8+8); else zero-fill role.
__global__ __launch_bounds__(NTHR) void lr_expand8(const f32x4* __restrict__ x,
                                                   const int* __restrict__ cum,
                                                   f32x4* __restrict__ out) {
    const int b  = blockIdx.y;
    const int bi = blockIdx.x;
    const int t  = threadIdx.x;
    const int* cb = cum + b * T_;

    if (bi < NEXP) {
        // ---- expand role ------------------------------------------------
        const int f0  = bi * G_;
        const int col = (t >= D4_) ? t - D4_ : t;   // 0..95, lane's column

        // Prefetch all 8 source rows (independent loads, overlap latency).
        f32x4 v[G_];
        #pragma unroll
        for (int j = 0; j < G_; ++j)
            v[j] = x[((size_t)b * T_ + f0 + j) * D4_ + col];

        // 9 boundaries, wave-uniform scalar loads (fully unrolled -> regs).
        int c[G_ + 1];
        c[0] = f0 ? cb[f0 - 1] : 0;
        #pragma unroll
        for (int j = 1; j <= G_; ++j)
            c[j] = cb[f0 + j - 1];

        if (c[0] >= ML_) return;                    // whole span clipped

        f32x4* ob = out + (size_t)b * ML_ * D4_;

        #pragma unroll
        for (int j = 0; j < G_; ++j) {
            int start = c[j];
            int end   = c[j + 1];
            if (end > ML_) end = ML_;               // clip at MAXLEN
            // 2-row windows: t<96 covers row r, t>=96 covers row r+1
            // (identical content) -> each wave stores 1 KB contiguous.
            int r = start;
            for (; r + 1 < end; r += 2)
                __builtin_nontemporal_store(v[j], &ob[(size_t)r * D4_ + t]);
            if (r < end && t < D4_)                 // odd-count tail row
                __builtin_nontemporal_store(v[j], &ob[(size_t)r * D4_ + t]);
        }
    } else {
        // ---- fill role: zero rows [min(total,ML), ML), contiguous slices
        const int fb    = bi - NEXP;                // 0..NFILL-1
        const int total = cb[T_ - 1];
        const int tr    = total < ML_ ? total : ML_;
        const int n     = (ML_ - tr) * D4_;         // float4 count to zero
        const int per   = (n + NFILL - 1) / NFILL;
        const int off   = fb * per;
        int cnt = n - off;
        if (cnt > per) cnt = per;
        if (cnt <= 0) return;
        f32x4* o = out + ((size_t)b * ML_ + tr) * D4_ + off;
        const f32x4 z = 0.f;
        for (int j = t; j < cnt; j += NTHR)
            __builtin_nontemporal_store(z, &o[j]);
    }
}

extern "C" void kernel_launch(void* const* d_in, const int* in_sizes, int n_in,
                              void* d_out, int out_size, void* d_ws, size_t ws_size,
                              hipStream_t stream) {
    const float* x   = (const float*)d_in[0];   // (B, T, D) fp32
    const int*   dur = (const int*)d_in[1];     // (B, T) int32
    // d_in[2] = max_len scalar (always 8192 here)

    float* out       = (float*)d_out;                   // (B, ML, D) fp32
    float* total_out = out + (size_t)B_ * ML_ * D_;     // (B,) as fp32
    int*   cum       = (int*)d_ws;                      // (B, T) scratch

    lr_scan<<<B_, T_, 0, stream>>>(dur, cum, total_out);
    lr_expand8<<<dim3(NEXP + NFILL, B_), NTHR, 0, stream>>>(
        (const f32x4*)x, cum, (f32x4*)out);
}